// Round 5
// baseline (211.961 us; speedup 1.0000x reference)
//
#include <hip/hip_runtime.h>
#include <cstdint>

#define EMBED 256
#define HEADS 8
#define LEVELS 4
#define POINTS 4
#define BS 2
#define NQ 16384
#define NV 21760          // 128*128+64*64+32*32+16*16
#define MQ (BS*NQ)        // 32768
#define MV (BS*NV)        // 43520
#define NBKT 512          // (BS) x 16x16 ref-grid buckets

typedef __attribute__((ext_vector_type(8))) short short8;
typedef __attribute__((ext_vector_type(4))) float f32x4;

__device__ __forceinline__ unsigned short f2bf(float f) {
    unsigned int u = __float_as_uint(f);
    u = (u + 0x7FFFu + ((u >> 16) & 1u)) >> 16;   // RNE
    return (unsigned short)u;
}
__device__ __forceinline__ float bf2f(unsigned short h) {
    return __uint_as_float(((unsigned int)h) << 16);
}
__device__ __forceinline__ void glds16(const unsigned short* g, unsigned short* l) {
    __builtin_amdgcn_global_load_lds((const __attribute__((address_space(1))) void*)g,
                                     (__attribute__((address_space(3))) void*)l, 16, 0, 0);
}

// ---------------------------------------------------------------------------
// prep_wt: Wt[n][k] = bf16(W[k][n]) for 6 weight matrices. grid (384, 6).
// ---------------------------------------------------------------------------
struct WtArgs {
    const float* src[6];
    unsigned short* dst[6];
    int n[6];
};
__global__ __launch_bounds__(256) void prep_wt(WtArgs a)
{
    const int g = blockIdx.y;
    const int N = a.n[g];
    const int e = blockIdx.x * 256 + threadIdx.x;
    if (e >= 256 * N) return;
    const int k = e / N, n = e - k * N;
    a.dst[g][(size_t)n * 256 + k] = f2bf(a.src[g][e]);
}

// ---------------------------------------------------------------------------
// Query bucket sort (locality for the sampler):
//   zero_k   : hist = 0
//   bucket_k : bkt[rb] = (b, qy, qx) from level-0 ref; hist[bkt]++
//   scan_k   : offs = exclusive_prefix(hist)   (1 block, 512 thr)
//   scatter_k: perm[atomic(offs[bkt])] = rb
// Result order within a bucket is non-stable, but each query's output is
// computed and written independently -> final d_out is deterministic.
// ---------------------------------------------------------------------------
__global__ __launch_bounds__(512) void zero_k(int* __restrict__ hist)
{
    hist[threadIdx.x] = 0;
}
__global__ __launch_bounds__(256) void bucket_k(
    const float* __restrict__ ref2d, int* __restrict__ bkt, int* __restrict__ hist)
{
    const int rb = blockIdx.x * 256 + threadIdx.x;
    const float x = ref2d[(size_t)rb * 8 + 0];
    const float y = ref2d[(size_t)rb * 8 + 1];
    const int qx = min(15, max(0, (int)(x * 16.f)));
    const int qy = min(15, max(0, (int)(y * 16.f)));
    const int bv = (rb >> 14) * 256 + qy * 16 + qx;
    bkt[rb] = bv;
    atomicAdd(&hist[bv], 1);
}
__global__ __launch_bounds__(512) void scan_k(
    const int* __restrict__ hist, int* __restrict__ offs)
{
    __shared__ int s[512];
    const int t = threadIdx.x;
    int v = hist[t];
    s[t] = v;
    __syncthreads();
    int acc = v;
#pragma unroll
    for (int o = 1; o < 512; o <<= 1) {
        int add = (t >= o) ? s[t - o] : 0;
        __syncthreads();
        acc += add;
        s[t] = acc;
        __syncthreads();
    }
    offs[t] = acc - v;   // exclusive
}
__global__ __launch_bounds__(256) void scatter_k(
    const int* __restrict__ bkt, int* __restrict__ offs, int* __restrict__ perm)
{
    const int rb = blockIdx.x * 256 + threadIdx.x;
    const int pos = atomicAdd(&offs[bkt[rb]], 1);
    perm[pos] = rb;
}

// ---------------------------------------------------------------------------
// gemm_big: out(M x NCOLS) = A(M x 256) @ Wt^T + bias (+res) [LN] [relu]
// ---------------------------------------------------------------------------
template<int NCOLS, int STAGEF32, int LNF, int RELUF>
__global__ __launch_bounds__(512) void gemm_big(
    const unsigned short* __restrict__ A,
    const float* __restrict__ Af, const float* __restrict__ A2f, int inner,
    const unsigned short* __restrict__ Bt,
    const float* __restrict__ bias0, const float* __restrict__ bias1,
    const float* __restrict__ res,
    const float* __restrict__ lng, const float* __restrict__ lnb,
    float* __restrict__ outf, unsigned short* __restrict__ outh)
{
    constexpr int FN = NCOLS / 64;
    __shared__ unsigned short As[128 * 32];
    __shared__ unsigned short Bs[NCOLS * 32];
    __shared__ float2 sdLN[LNF ? 128 : 1][4];

    const int t = threadIdx.x, l = t & 63, w = t >> 6;
    const int wm = w >> 2, wn = w & 3;
    const int frow = l & 15, fgrp = l >> 4;
    const size_t brow = (size_t)blockIdx.x * 128;

    const int fslot = fgrp ^ ((frow & 3) ^ ((frow >> 2) & 3));
    const int srow = l >> 2;
    const int sswz = (l & 3) ^ ((srow & 3) ^ ((srow >> 2) & 3));
    const unsigned short* gB0 = Bt + ((size_t)(w * 16 + srow)) * 256 + sswz * 8;

    const unsigned short* gA = nullptr;
    const float* srcA = nullptr; const float* srcA2 = nullptr;
    int arow_s = 0, aslot_s = 0, aswz_s = 0;
    if constexpr (STAGEF32) {
        arow_s = t >> 2; aslot_s = t & 3;
        const int grow = (int)brow + arow_s;
        const int bidx = grow / inner, nn = grow - bidx * inner;
        srcA = Af + (size_t)(nn * BS + bidx) * 256;
        if (A2f) srcA2 = A2f + (size_t)(nn * BS + bidx) * 256;
        aswz_s = aslot_s ^ ((arow_s & 3) ^ ((arow_s >> 2) & 3));
    } else {
        gA = A + (brow + (size_t)(w * 16 + srow)) * 256 + sswz * 8;
    }

    f32x4 acc[4][FN];
#pragma unroll
    for (int i = 0; i < 4; ++i)
#pragma unroll
        for (int j = 0; j < FN; ++j) acc[i][j] = f32x4{0.f, 0.f, 0.f, 0.f};

    float4 pA0, pA1, pC0, pC1;
    if constexpr (STAGEF32) {
        pA0 = *(const float4*)(srcA + aslot_s * 8);
        pA1 = *(const float4*)(srcA + aslot_s * 8 + 4);
        if (srcA2) { pC0 = *(const float4*)(srcA2 + aslot_s * 8);
                     pC1 = *(const float4*)(srcA2 + aslot_s * 8 + 4); }
    }

    for (int k0 = 0; k0 < 256; k0 += 32) {
        glds16(gB0 + k0,         (unsigned short*)&Bs[w * 512]);
        glds16(gB0 + 32768 + k0, (unsigned short*)&Bs[(w + 8) * 512]);
        if constexpr (NCOLS == 384)
            glds16(gB0 + 65536 + k0, (unsigned short*)&Bs[(w + 16) * 512]);

        if constexpr (STAGEF32) {
            float c[8] = {pA0.x, pA0.y, pA0.z, pA0.w, pA1.x, pA1.y, pA1.z, pA1.w};
            if (srcA2) {
                c[0] += pC0.x; c[1] += pC0.y; c[2] += pC0.z; c[3] += pC0.w;
                c[4] += pC1.x; c[5] += pC1.y; c[6] += pC1.z; c[7] += pC1.w;
            }
            short8 pk;
#pragma unroll
            for (int i = 0; i < 8; ++i) pk[i] = (short)f2bf(c[i]);
            *reinterpret_cast<short8*>(&As[arow_s * 32 + aswz_s * 8]) = pk;
            if (k0 + 32 < 256) {
                pA0 = *(const float4*)(srcA + k0 + 32 + aslot_s * 8);
                pA1 = *(const float4*)(srcA + k0 + 32 + aslot_s * 8 + 4);
                if (srcA2) { pC0 = *(const float4*)(srcA2 + k0 + 32 + aslot_s * 8);
                             pC1 = *(const float4*)(srcA2 + k0 + 32 + aslot_s * 8 + 4); }
            }
        } else {
            glds16(gA + k0, (unsigned short*)&As[w * 512]);
        }
        __syncthreads();

        short8 af[4]; short8 bq[FN];
#pragma unroll
        for (int fm = 0; fm < 4; ++fm)
            af[fm] = *reinterpret_cast<const short8*>(&As[(wm * 64 + fm * 16 + frow) * 32 + fslot * 8]);
#pragma unroll
        for (int fn = 0; fn < FN; ++fn)
            bq[fn] = *reinterpret_cast<const short8*>(&Bs[(wn * (NCOLS / 4) + fn * 16 + frow) * 32 + fslot * 8]);
#pragma unroll
        for (int fm = 0; fm < 4; ++fm)
#pragma unroll
            for (int fn = 0; fn < FN; ++fn)
                acc[fm][fn] = __builtin_amdgcn_mfma_f32_16x16x32_bf16(af[fm], bq[fn], acc[fm][fn], 0, 0, 0);
        __syncthreads();
    }

    int cols[FN]; float bi[FN];
#pragma unroll
    for (int fn = 0; fn < FN; ++fn) {
        const int col = wn * (NCOLS / 4) + fn * 16 + frow;
        cols[fn] = col;
        float b = 0.f;
        if (bias0) {
            if (NCOLS == 384) b = (col < 256) ? bias0[col] : bias1[col - 256];
            else              b = bias0[col];
        }
        bi[fn] = b;
    }
#pragma unroll
    for (int fm = 0; fm < 4; ++fm)
#pragma unroll
        for (int j = 0; j < 4; ++j) {
            const size_t row = brow + wm * 64 + fm * 16 + fgrp * 4 + j;
#pragma unroll
            for (int fn = 0; fn < FN; ++fn) {
                float x = acc[fm][fn][j] + bi[fn];
                if (res)   x += res[row * NCOLS + cols[fn]];
                if (RELUF) x = fmaxf(x, 0.f);
                acc[fm][fn][j] = x;
            }
        }

    if constexpr (LNF) {
#pragma unroll
        for (int fm = 0; fm < 4; ++fm)
#pragma unroll
            for (int j = 0; j < 4; ++j) {
                float s1 = 0.f, s2 = 0.f;
#pragma unroll
                for (int fn = 0; fn < FN; ++fn) { const float x = acc[fm][fn][j]; s1 += x; s2 += x * x; }
#pragma unroll
                for (int o = 1; o < 16; o <<= 1) { s1 += __shfl_xor(s1, o); s2 += __shfl_xor(s2, o); }
                if (frow == 0)
                    sdLN[wm * 64 + fm * 16 + fgrp * 4 + j][wn] = make_float2(s1, s2);
            }
        __syncthreads();
        float gv[FN], bv[FN];
#pragma unroll
        for (int fn = 0; fn < FN; ++fn) { gv[fn] = lng[cols[fn]]; bv[fn] = lnb[cols[fn]]; }
#pragma unroll
        for (int fm = 0; fm < 4; ++fm)
#pragma unroll
            for (int j = 0; j < 4; ++j) {
                const int rl = wm * 64 + fm * 16 + fgrp * 4 + j;
                const float2 p0 = sdLN[rl][0], p1 = sdLN[rl][1], p2 = sdLN[rl][2], p3 = sdLN[rl][3];
                const float s1 = p0.x + p1.x + p2.x + p3.x;
                const float s2 = p0.y + p1.y + p2.y + p3.y;
                const float mu = s1 * (1.f / 256.f);
                const float var = s2 * (1.f / 256.f) - mu * mu;
                const float rstd = rsqrtf(var + 1e-5f);
                const size_t row = brow + rl;
#pragma unroll
                for (int fn = 0; fn < FN; ++fn) {
                    const float y = (acc[fm][fn][j] - mu) * rstd * gv[fn] + bv[fn];
                    if (outf) outf[row * NCOLS + cols[fn]] = y;
                    if (outh) outh[row * NCOLS + cols[fn]] = f2bf(y);
                }
            }
    } else {
#pragma unroll
        for (int fm = 0; fm < 4; ++fm)
#pragma unroll
            for (int j = 0; j < 4; ++j) {
                const size_t row = brow + wm * 64 + fm * 16 + fgrp * 4 + j;
#pragma unroll
                for (int fn = 0; fn < FN; ++fn) {
                    const float x = acc[fm][fn][j];
                    if (outf) outf[row * NCOLS + cols[fn]] = x;
                    if (outh) outh[row * NCOLS + cols[fn]] = f2bf(x);
                }
            }
    }
}

// ---------------------------------------------------------------------------
// ffn_fused: per 64-row block — h = relu(X@W1); out = LN2(h@W2 + X).
// ---------------------------------------------------------------------------
__global__ __launch_bounds__(512) void ffn_fused(
    const unsigned short* __restrict__ X,
    const unsigned short* __restrict__ W1t, const unsigned short* __restrict__ W2t,
    const float* __restrict__ lng, const float* __restrict__ lnb,
    float* __restrict__ outf)
{
    __shared__ unsigned short As[64 * 32];
    __shared__ unsigned short Bs[256 * 32];
    __shared__ unsigned short Hs[64 * 256];
    __shared__ float2 sdLN[64][4];

    const int t = threadIdx.x, l = t & 63, w = t >> 6;
    const int wm = w >> 2, wn = w & 3;
    const int frow = l & 15, fgrp = l >> 4;
    const size_t brow = (size_t)blockIdx.x * 64;

    const int fslot = fgrp ^ ((frow & 3) ^ ((frow >> 2) & 3));
    const int srow = l >> 2;
    const int sswz = (l & 3) ^ ((srow & 3) ^ ((srow >> 2) & 3));

    const unsigned short* gX  = X + (brow + (size_t)((w & 3) * 16 + srow)) * 256 + sswz * 8;
    const unsigned short* gW1 = W1t + ((size_t)(w * 16 + srow)) * 256 + sswz * 8;
    const unsigned short* gW2 = W2t + ((size_t)(w * 16 + srow)) * 256 + sswz * 8;

    f32x4 acc[2][4];

#pragma unroll
    for (int i = 0; i < 2; ++i)
#pragma unroll
        for (int j = 0; j < 4; ++j) acc[i][j] = f32x4{0.f, 0.f, 0.f, 0.f};

    for (int k0 = 0; k0 < 256; k0 += 32) {
        glds16(gW1 + k0,         (unsigned short*)&Bs[w * 512]);
        glds16(gW1 + 32768 + k0, (unsigned short*)&Bs[(w + 8) * 512]);
        if (w < 4) glds16(gX + k0, (unsigned short*)&As[w * 512]);
        __syncthreads();

        short8 af[2], bq[4];
#pragma unroll
        for (int fm = 0; fm < 2; ++fm)
            af[fm] = *reinterpret_cast<const short8*>(&As[(wm * 32 + fm * 16 + frow) * 32 + fslot * 8]);
#pragma unroll
        for (int fn = 0; fn < 4; ++fn)
            bq[fn] = *reinterpret_cast<const short8*>(&Bs[(wn * 64 + fn * 16 + frow) * 32 + fslot * 8]);
#pragma unroll
        for (int fm = 0; fm < 2; ++fm)
#pragma unroll
            for (int fn = 0; fn < 4; ++fn)
                acc[fm][fn] = __builtin_amdgcn_mfma_f32_16x16x32_bf16(af[fm], bq[fn], acc[fm][fn], 0, 0, 0);
        __syncthreads();
    }

#pragma unroll
    for (int fm = 0; fm < 2; ++fm)
#pragma unroll
        for (int fn = 0; fn < 4; ++fn) {
            const int col = wn * 64 + fn * 16 + frow;
#pragma unroll
            for (int j = 0; j < 4; ++j) {
                const int row = wm * 32 + fm * 16 + fgrp * 4 + j;
                const int ss = (col >> 3) ^ (row & 7);
                Hs[row * 256 + ss * 8 + (col & 7)] = f2bf(fmaxf(acc[fm][fn][j], 0.f));
            }
        }
    __syncthreads();

#pragma unroll
    for (int i = 0; i < 2; ++i)
#pragma unroll
        for (int j = 0; j < 4; ++j) acc[i][j] = f32x4{0.f, 0.f, 0.f, 0.f};

    for (int k0 = 0; k0 < 256; k0 += 32) {
        glds16(gW2 + k0,         (unsigned short*)&Bs[w * 512]);
        glds16(gW2 + 32768 + k0, (unsigned short*)&Bs[(w + 8) * 512]);
        __syncthreads();

        short8 af[2], bq[4];
#pragma unroll
        for (int fm = 0; fm < 2; ++fm) {
            const int row = wm * 32 + fm * 16 + frow;
            const int ksg = (k0 >> 3) + fgrp;
            const int ss = ksg ^ (row & 7);
            af[fm] = *reinterpret_cast<const short8*>(&Hs[row * 256 + ss * 8]);
        }
#pragma unroll
        for (int fn = 0; fn < 4; ++fn)
            bq[fn] = *reinterpret_cast<const short8*>(&Bs[(wn * 64 + fn * 16 + frow) * 32 + fslot * 8]);
#pragma unroll
        for (int fm = 0; fm < 2; ++fm)
#pragma unroll
            for (int fn = 0; fn < 4; ++fn)
                acc[fm][fn] = __builtin_amdgcn_mfma_f32_16x16x32_bf16(af[fm], bq[fn], acc[fm][fn], 0, 0, 0);
        __syncthreads();
    }

#pragma unroll
    for (int fm = 0; fm < 2; ++fm)
#pragma unroll
        for (int fn = 0; fn < 4; ++fn) {
            const int col = wn * 64 + fn * 16 + frow;
#pragma unroll
            for (int j = 0; j < 4; ++j) {
                const size_t row = brow + wm * 32 + fm * 16 + fgrp * 4 + j;
                acc[fm][fn][j] += bf2f(X[row * 256 + col]);
            }
        }
#pragma unroll
    for (int fm = 0; fm < 2; ++fm)
#pragma unroll
        for (int j = 0; j < 4; ++j) {
            float s1 = 0.f, s2 = 0.f;
#pragma unroll
            for (int fn = 0; fn < 4; ++fn) { const float x = acc[fm][fn][j]; s1 += x; s2 += x * x; }
#pragma unroll
            for (int o = 1; o < 16; o <<= 1) { s1 += __shfl_xor(s1, o); s2 += __shfl_xor(s2, o); }
            if (frow == 0)
                sdLN[wm * 32 + fm * 16 + fgrp * 4 + j][wn] = make_float2(s1, s2);
        }
    __syncthreads();
#pragma unroll
    for (int fm = 0; fm < 2; ++fm)
#pragma unroll
        for (int j = 0; j < 4; ++j) {
            const int rl = wm * 32 + fm * 16 + fgrp * 4 + j;
            const float2 p0 = sdLN[rl][0], p1 = sdLN[rl][1], p2 = sdLN[rl][2], p3 = sdLN[rl][3];
            const float s1 = p0.x + p1.x + p2.x + p3.x;
            const float s2 = p0.y + p1.y + p2.y + p3.y;
            const float mu = s1 * (1.f / 256.f);
            const float var = s2 * (1.f / 256.f) - mu * mu;
            const float rstd = rsqrtf(var + 1e-5f);
            const size_t row = brow + rl;
#pragma unroll
            for (int fn = 0; fn < 4; ++fn) {
                const int col = wn * 64 + fn * 16 + frow;
                outf[row * 256 + col] = (acc[fm][fn][j] - mu) * rstd * lng[col] + lnb[col];
            }
        }
}

// ---------------------------------------------------------------------------
// Deformable sampler v5: processes PERMUTED queries (bucket-sorted by ref_2d)
// with XCD-aware block swizzle -> per-XCD L2 locality on v gathers.
// Structure otherwise as v4 (4 q/block, 2-deep pipelined gather).
// ---------------------------------------------------------------------------
#define LDDESC(dst, base)                         \
    _Pragma("unroll")                             \
    for (int j = 0; j < 16; ++j) dst[j] = dp[(base) + j];
#define LDRAW(dst, dsc)                           \
    _Pragma("unroll")                             \
    for (int j = 0; j < 16; ++j) dst[j] = *(const uint2*)(vd + dsc[j].y);
#define FMA16(dsc, raw)                           \
    _Pragma("unroll")                             \
    for (int j = 0; j < 16; ++j) {                \
        const float wgt = __uint_as_float(dsc[j].x);            \
        a0 += wgt * __uint_as_float(raw[j].x << 16);            \
        a1 += wgt * __uint_as_float(raw[j].x & 0xFFFF0000u);    \
        a2 += wgt * __uint_as_float(raw[j].y << 16);            \
        a3 += wgt * __uint_as_float(raw[j].y & 0xFFFF0000u);    \
    }

__global__ __launch_bounds__(256) void sampler_k(
    const unsigned short* __restrict__ oa,    // [MQ][384]: off(256) | aw(128)
    const float* __restrict__ ref2d,          // [MQ][8]
    const unsigned short* __restrict__ v,     // [MV][256]
    const int* __restrict__ perm,             // [MQ] bucket-sorted query ids
    unsigned short* __restrict__ outh)        // [MQ][256] nq-major
{
    // XCD swizzle: 8192 blocks, 8 XCDs -> XCD x gets contiguous perm range
    const int bid = blockIdx.x;
    const int sbid = (bid & 7) * (MQ / 4 / 8) + (bid >> 3);
    const int q0 = sbid * 4;
    const int t = threadIdx.x;

    __shared__ int s_rb[4];
    __shared__ float s_off[4][256];
    __shared__ float s_aw[4][128];
    __shared__ float s_ref[4][8];
    __shared__ uint2 s_d[4][8][65];

    if (t < 4) s_rb[t] = perm[q0 + t];
    __syncthreads();

    {
        const int tq = t >> 6, c = (t & 63) * 4;
        const ushort4 u = *(const ushort4*)(oa + (size_t)s_rb[tq] * 384 + c);
        s_off[tq][c + 0] = bf2f(u.x); s_off[tq][c + 1] = bf2f(u.y);
        s_off[tq][c + 2] = bf2f(u.z); s_off[tq][c + 3] = bf2f(u.w);
    }
    if (t < 128) {
        const int tq = t >> 5, c = (t & 31) * 4;
        const ushort4 u = *(const ushort4*)(oa + (size_t)s_rb[tq] * 384 + 256 + c);
        s_aw[tq][c + 0] = bf2f(u.x); s_aw[tq][c + 1] = bf2f(u.y);
        s_aw[tq][c + 2] = bf2f(u.z); s_aw[tq][c + 3] = bf2f(u.w);
    }
    if (t < 32) {
        const int tq = t >> 3;
        s_ref[tq][t & 7] = ref2d[(size_t)s_rb[tq] * 8 + (t & 7)];
    }
    __syncthreads();

    if (t < 32) {                       // softmax per (query, head) over 16
        const int tq = t >> 3, h = t & 7;
        float* a = s_aw[tq] + h * 16;
        float m = -1e30f;
#pragma unroll
        for (int i = 0; i < 16; ++i) m = fmaxf(m, a[i]);
        float e[16], s = 0.f;
#pragma unroll
        for (int i = 0; i < 16; ++i) { e[i] = __expf(a[i] - m); s += e[i]; }
        const float inv = 1.f / s;
#pragma unroll
        for (int i = 0; i < 16; ++i) a[i] = e[i] * inv;
    }
    __syncthreads();

#pragma unroll
    for (int it = 0; it < 2; ++it) {    // 512 descriptors, 2 per thread
        const int item = t + it * 256;
        const int tq = item >> 7, hlp = item & 127;
        const int h = hlp >> 4, lp = hlp & 15, li = lp >> 2;
        const int Wl[4]  = {128, 64, 32, 16};
        const int S0l[4] = {0, 16384, 20480, 21504};
        const int Wi = Wl[li]; const float Wf = (float)Wi;
        const int b = s_rb[tq] >> 14;
        const float x = (s_ref[tq][li * 2 + 0] + s_off[tq][hlp * 2 + 0] / Wf) * Wf - 0.5f;
        const float y = (s_ref[tq][li * 2 + 1] + s_off[tq][hlp * 2 + 1] / Wf) * Wf - 0.5f;
        const float x0f = floorf(x), y0f = floorf(y);
        const float lx = x - x0f, ly = y - y0f;
        const int x0 = (int)x0f, y0 = (int)y0f;
        const float a = s_aw[tq][hlp];
        const float cw[4] = {(1.f - lx) * (1.f - ly) * a, lx * (1.f - ly) * a,
                             (1.f - lx) * ly * a,          lx * ly * a};
        const int base = b * NV + S0l[li];
#pragma unroll
        for (int c = 0; c < 4; ++c) {
            const int xi = x0 + (c & 1), yi = y0 + (c >> 1);
            const bool val = (xi >= 0) & (xi < Wi) & (yi >= 0) & (yi < Wi);
            const int xc = min(max(xi, 0), Wi - 1), yc = min(max(yi, 0), Wi - 1);
            const unsigned int ofs = (unsigned int)(base + yc * Wi + xc) * 256u + h * 32;
            s_d[tq][h][lp * 4 + c] = make_uint2(__float_as_uint(val ? cw[c] : 0.f), ofs);
        }
    }
    __syncthreads();

    const int tq = t >> 6, l = t & 63, h = l >> 3, dq = l & 7;
    const int rb = s_rb[tq], b = rb >> 14, qi = rb & (NQ - 1);
    const unsigned short* vd = v + dq * 4;
    const uint2* dp = &s_d[tq][h][0];
    float a0 = 0.f, a1 = 0.f, a2 = 0.f, a3 = 0.f;

    uint2 dA[16], dB[16], rA[16], rB[16];
    LDDESC(dA, 0)
    LDRAW(rA, dA)
    LDDESC(dB, 16)
    LDRAW(rB, dB)
    FMA16(dA, rA)
    LDDESC(dA, 32)
    LDRAW(rA, dA)
    FMA16(dB, rB)
    LDDESC(dB, 48)
    LDRAW(rB, dB)
    FMA16(dA, rA)
    FMA16(dB, rB)

    ushort4 o; o.x = f2bf(a0); o.y = f2bf(a1); o.z = f2bf(a2); o.w = f2bf(a3);
    *(ushort4*)(outh + (size_t)(qi * BS + b) * 256 + h * 32 + dq * 4) = o;
}

// ---------------------------------------------------------------------------
extern "C" void kernel_launch(void* const* d_in, const int* in_sizes, int n_in,
                              void* d_out, int out_size, void* d_ws, size_t ws_size,
                              hipStream_t stream)
{
    const float* lidar  = (const float*)d_in[0];
    const float* feat   = (const float*)d_in[1];
    const float* ref2d  = (const float*)d_in[2];
    const float* q_pose = (const float*)d_in[5];
    const float* W_off  = (const float*)d_in[6];
    const float* b_off  = (const float*)d_in[7];
    const float* W_attn = (const float*)d_in[8];
    const float* b_attn = (const float*)d_in[9];
    const float* W_val  = (const float*)d_in[10];
    const float* b_val  = (const float*)d_in[11];
    const float* W_out  = (const float*)d_in[12];
    const float* b_out  = (const float*)d_in[13];
    const float* ln1_g  = (const float*)d_in[14];
    const float* ln1_b  = (const float*)d_in[15];
    const float* ffn_w1 = (const float*)d_in[16];
    const float* ffn_w2 = (const float*)d_in[17];
    const float* ln2_g  = (const float*)d_in[18];
    const float* ln2_b  = (const float*)d_in[19];

    float* out = (float*)d_out;
    char*  ws  = (char*)d_ws;

    // byte offsets; high-water ~82.1 MB
    unsigned short* vb   = (unsigned short*)(ws + 0);          // 22.28 MB
    unsigned short* oa   = (unsigned short*)(ws + 22282240);   // 25.17 MB
    unsigned short* smp  = (unsigned short*)(ws + 47448064);   // 16.78 MB
    unsigned short* xln  = (unsigned short*)(ws + 64225280);   // 16.78 MB
    unsigned short* wt   = (unsigned short*)(ws + 81002496);   // 0.72 MB
    int* perm = (int*)(ws + 81788928);                         // 128 KB
    int* bkt  = (int*)(ws + 81920000);                         // 128 KB
    int* hist = (int*)(ws + 82051072);                         // 2 KB
    int* offs = (int*)(ws + 82053120);                         // 2 KB
    unsigned short* wt_val = wt;
    unsigned short* wt_oa  = wt + 65536;          // [384][256]
    unsigned short* wt_out = wt + 163840;
    unsigned short* wt_f1  = wt + 229376;
    unsigned short* wt_f2  = wt + 294912;

    WtArgs wa;
    wa.src[0] = W_val;  wa.dst[0] = wt_val;          wa.n[0] = 256;
    wa.src[1] = W_off;  wa.dst[1] = wt_oa;           wa.n[1] = 256;
    wa.src[2] = W_attn; wa.dst[2] = wt_oa + 65536;   wa.n[2] = 128;
    wa.src[3] = W_out;  wa.dst[3] = wt_out;          wa.n[3] = 256;
    wa.src[4] = ffn_w1; wa.dst[4] = wt_f1;           wa.n[4] = 256;
    wa.src[5] = ffn_w2; wa.dst[5] = wt_f2;           wa.n[5] = 256;
    prep_wt<<<dim3(384, 6), dim3(256), 0, stream>>>(wa);

    // query bucket sort (runs concurrently-ish with projections on counters,
    // serialized on stream but each is tiny)
    zero_k<<<dim3(1), dim3(512), 0, stream>>>(hist);
    bucket_k<<<dim3(MQ / 256), dim3(256), 0, stream>>>(ref2d, bkt, hist);
    scan_k<<<dim3(1), dim3(512), 0, stream>>>(hist, offs);
    scatter_k<<<dim3(MQ / 256), dim3(256), 0, stream>>>(bkt, offs, perm);

    // value projection: feat f32 (remap inner=NV) -> vb bf16
    gemm_big<256, 1, 0, 0><<<dim3(MV / 128), dim3(512), 0, stream>>>(
        nullptr, feat, nullptr, NV, wt_val, b_val, nullptr,
        nullptr, nullptr, nullptr, nullptr, vb);

    // off+attn merged: (lidar+q_pose) f32 -> oa bf16 [MQ][384]
    gemm_big<384, 1, 0, 0><<<dim3(MQ / 128), dim3(512), 0, stream>>>(
        nullptr, lidar, q_pose, NQ, wt_oa, b_off, b_attn,
        nullptr, nullptr, nullptr, nullptr, oa);

    // deformable sampling (+softmax), bucket-sorted order -> smp bf16 nq-major
    sampler_k<<<dim3(MQ / 4), dim3(256), 0, stream>>>(oa, ref2d, vb, perm, smp);

    // out-proj + bias + residual(lidar f32) + LN1 -> xln bf16 only
    gemm_big<256, 0, 1, 0><<<dim3(MQ / 128), dim3(512), 0, stream>>>(
        smp, nullptr, nullptr, 0, wt_out, b_out, nullptr,
        lidar, ln1_g, ln1_b, nullptr, xln);

    // fused FFN1+FFN2+LN2 -> d_out f32
    ffn_fused<<<dim3(MQ / 64), dim3(512), 0, stream>>>(
        xln, wt_f1, wt_f2, ln2_g, ln2_b, out);
}